// Round 4
// baseline (683.824 us; speedup 1.0000x reference)
//
#include <hip/hip_runtime.h>
#include <hip/hip_bf16.h>

#define N_NODES 512
#define N_EDGES (512 * 512)
#define NBLK 256                 // sort blocks
#define EPB (N_EDGES / NBLK)     // 1024 edges per sort block

typedef __attribute__((ext_vector_type(2))) _Float16 half2v;

#if defined(__has_builtin)
#if __has_builtin(__builtin_amdgcn_fdot2)
#define FDOT2(a, b, c) __builtin_amdgcn_fdot2((a), (b), (c), false)
#endif
#endif
#ifndef FDOT2
static __device__ inline float fdot2_asm(half2v a, half2v b, float c) {
    float d;
    asm("v_dot2_f32_f16 %0, %1, %2, %3" : "=v"(d) : "v"(a), "v"(b), "v"(c));
    return d;
}
#define FDOT2(a, b, c) fdot2_asm((a), (b), (c))
#endif

static __device__ inline unsigned pack_h2(float x, float y) {
    union { _Float16 h[2]; unsigned u; } c;
    c.h[0] = (_Float16)x;
    c.h[1] = (_Float16)y;
    return c.u;
}
static __device__ inline half2v bits_h2(int b) {
    union { int i; half2v h; } c;
    c.i = b;
    return c.h;
}

// ---------------------------------------------------------------------------
// count: per-block LDS histogram -> TRANSPOSED bcnt_t[bucket][block] (coalesced
// colscan reads). Also zeros the agg1/agg2/agg3 region (replaces memsetAsync).
// ---------------------------------------------------------------------------
__global__ __launch_bounds__(256) void count_kernel(const int* __restrict__ dst,
                                                    int* __restrict__ bcnt_t,
                                                    float* __restrict__ aggz) {
    __shared__ int h[N_NODES];
    int tid = threadIdx.x;
    int b = blockIdx.x;
    h[tid] = 0;
    h[tid + 256] = 0;
    int gt = b * 256 + tid;
    if (gt < 512 * (36 + 24 + 5)) aggz[gt] = 0.f;   // zero aggs (contiguous)
    __syncthreads();
#pragma unroll
    for (int k = 0; k < EPB / 256; k++)
        atomicAdd(&h[dst[b * EPB + k * 256 + tid]], 1);
    __syncthreads();
    bcnt_t[tid * NBLK + b] = h[tid];
    bcnt_t[(tid + 256) * NBLK + b] = h[tid + 256];
}

// colscan: one block per bucket t. Coalesced read; exclusive prefix over sort
// blocks -> pre[b][t]; total -> tot[t]. Tail: rows 506..511 of bcnt_t are
// re-zeroed AFTER this block's read — they alias the done1/2/3 counters used
// by the fused edge kernels (read-before-zero, disjoint rows: race-free).
__global__ __launch_bounds__(NBLK) void colscan_kernel(const int* __restrict__ bcnt_t,
                                                       int* __restrict__ pre,
                                                       int* __restrict__ tot,
                                                       int* __restrict__ bz) {
    __shared__ int buf[NBLK];
    int t = blockIdx.x;
    int b = threadIdx.x;
    int v = bcnt_t[t * NBLK + b];                   // coalesced
    buf[b] = v;
    __syncthreads();
    for (int d = 1; d < NBLK; d <<= 1) {
        int add = (b >= d) ? buf[b - d] : 0;
        __syncthreads();
        buf[b] += add;
        __syncthreads();
    }
    pre[b * N_NODES + t] = buf[b] - v;
    if (b == NBLK - 1) tot[t] = buf[b];
    if (t >= N_NODES - 6) bz[t * NBLK + b] = 0;     // zero done counters
}

// offs: scan of 512 bucket totals -> offs[513].
__global__ __launch_bounds__(512) void offs_kernel(const int* __restrict__ tot,
                                                   int* __restrict__ offs) {
    __shared__ int buf[N_NODES];
    int t = threadIdx.x;
    int v = tot[t];
    buf[t] = v;
    __syncthreads();
    for (int d = 1; d < N_NODES; d <<= 1) {
        int add = (t >= d) ? buf[t - d] : 0;
        __syncthreads();
        buf[t] += add;
        __syncthreads();
    }
    offs[t + 1] = buf[t];
    if (t == 0) offs[0] = 0;
}

// scatter: LDS cursor seeded from offs[t] + pre[b][t]; LDS atomics only.
__global__ __launch_bounds__(256) void scatter_kernel(const int* __restrict__ src,
                                                      const int* __restrict__ dst,
                                                      const float* __restrict__ ea,
                                                      const int* __restrict__ pre,
                                                      const int* __restrict__ offs,
                                                      int4* __restrict__ ed4) {
    __shared__ int lcur[N_NODES];
    int tid = threadIdx.x;
    int b = blockIdx.x;
    lcur[tid] = offs[tid] + pre[b * N_NODES + tid];
    lcur[tid + 256] = offs[tid + 256] + pre[b * N_NODES + tid + 256];
    __syncthreads();
#pragma unroll
    for (int k = 0; k < EPB / 256; k++) {
        int e = b * EPB + k * 256 + tid;
        const float* a = ea + (size_t)e * 6;
        float a0 = a[0], a1 = a[1], a2 = a[2], a3 = a[3], a4 = a[4], a5 = a[5];
        int p = atomicAdd(&lcur[dst[e]], 1);
        int4 r;
        r.x = (int)pack_h2(a0, a1);
        r.y = (int)pack_h2(a2, a3);
        r.z = (int)pack_h2(a4, a5);
        r.w = src[e];
        ed4[p] = r;
    }
}

// ---------------------------------------------------------------------------
// NNConv edges + FUSED finalize. Direct uniform VMEM/SMEM record loads (R1's
// proven-best memory path), 8-edge unrolled groups with a MASKED final group
// (no serial scalar tail). Lane t (< A) owns input-feature i = t/OPL and OG
// consecutive outputs. After the per-block combine (global atomicAdd), the
// LAST block of node n (device-scope done counter + threadfence) applies
// mean + root + bias + relu and writes hout — eliminates nnconv_fin launches.
// ---------------------------------------------------------------------------
template <int CIN, int COUT, int OG, int BLK, int G>
__global__ __launch_bounds__(BLK) void nnconv_edges(
    const float* __restrict__ hprev,  // [512, CIN]
    const int4* __restrict__ ed4,     // [E] sorted-by-dst edge records
    const int* __restrict__ offs,     // [513]
    const float* __restrict__ We,     // [6, CIN*COUT]
    const float* __restrict__ be,     // [CIN*COUT]
    const float* __restrict__ root,   // [CIN, COUT]
    const float* __restrict__ bias,   // [COUT]
    float* __restrict__ agg,          // [512, COUT] pre-zeroed
    int* __restrict__ done,           // [512] pre-zeroed
    float* __restrict__ hout)         // [512, COUT]
{
    constexpr int J = CIN * COUT;
    constexpr int OPL = COUT / OG;   // o-groups per input feature
    constexpr int A = CIN * OPL;     // active lanes

    __shared__ float lds_acc[J];
    __shared__ int lastf;

    const int n = blockIdx.x / G;
    const int g = blockIdx.x % G;
    const int tid = threadIdx.x;
    const bool act = (tid < A);
    const int i = act ? tid / OPL : 0;
    const int og = act ? (tid % OPL) * OG : 0;

    half2v wrp[OG][3];
    float ber[OG], acc[OG];
#pragma unroll
    for (int k = 0; k < OG; k++) {
        acc[k] = 0.f;
        int j = i * COUT + og + k;
        if (act) {
            ber[k] = be[j];
#pragma unroll
            for (int t = 0; t < 3; t++)
                wrp[k][t] = bits_h2((int)pack_h2(We[(2 * t) * J + j], We[(2 * t + 1) * J + j]));
        } else {
            ber[k] = 0.f;
#pragma unroll
            for (int t = 0; t < 3; t++) wrp[k][t] = bits_h2(0);
        }
    }

    const int start = offs[n];
    const int end = offs[n + 1];
    const int len = end - start;
    const int per = (len + G - 1) / G;
    int p = start + g * per;
    int p1 = p + per;
    if (p > end) p = end;
    if (p1 > end) p1 = end;

    const float* hp_i = hprev + i;   // per-lane feature-column base

    // full 8-edge groups: uniform record loads (scalarize to SMEM), 8
    // independent gathers, then 8x compute — ILP 8 per wave, multi-wave TLP
    // covers the residual latency.
    for (; p + 8 <= p1; p += 8) {
        int4 e[8];
#pragma unroll
        for (int u = 0; u < 8; u++) e[u] = ed4[p + u];
        float xg[8];
#pragma unroll
        for (int u = 0; u < 8; u++) xg[u] = hp_i[(e[u].w & (N_NODES - 1)) * CIN];
#pragma unroll
        for (int u = 0; u < 8; u++) {
            half2v e01 = bits_h2(e[u].x), e23 = bits_h2(e[u].y), e45 = bits_h2(e[u].z);
#pragma unroll
            for (int k = 0; k < OG; k++) {
                float z = FDOT2(e45, wrp[k][2],
                        FDOT2(e23, wrp[k][1],
                        FDOT2(e01, wrp[k][0], ber[k])));
                acc[k] = fmaf(xg[u], fmaxf(z, 0.f), acc[k]);
            }
        }
    }
    // masked final group (uniform mask — no divergence): zero record gives
    // z = be (finite), xv = 0 -> contribution exactly 0.
    if (p < p1) {
        int4 e[8];
        float xg[8];
#pragma unroll
        for (int u = 0; u < 8; u++)
            e[u] = (p + u < p1) ? ed4[p + u] : make_int4(0, 0, 0, 0);
#pragma unroll
        for (int u = 0; u < 8; u++)
            xg[u] = (p + u < p1) ? hp_i[(e[u].w & (N_NODES - 1)) * CIN] : 0.f;
#pragma unroll
        for (int u = 0; u < 8; u++) {
            half2v e01 = bits_h2(e[u].x), e23 = bits_h2(e[u].y), e45 = bits_h2(e[u].z);
#pragma unroll
            for (int k = 0; k < OG; k++) {
                float z = FDOT2(e45, wrp[k][2],
                        FDOT2(e23, wrp[k][1],
                        FDOT2(e01, wrp[k][0], ber[k])));
                acc[k] = fmaf(xg[u], fmaxf(z, 0.f), acc[k]);
            }
        }
    }

    // ---- combine partials into agg[n] ----
    if constexpr (CIN == 1) {
        if (act) atomicAdd(&agg[n * COUT + og], acc[0]);
    } else {
        if (act) {
#pragma unroll
            for (int k = 0; k < OG; k++) lds_acc[i * COUT + og + k] = acc[k];
        }
        __syncthreads();
        if (tid < COUT) {
            float sum = 0.f;
#pragma unroll
            for (int ii = 0; ii < CIN; ii++) sum += lds_acc[ii * COUT + tid];
            atomicAdd(&agg[n * COUT + tid], sum);
        }
    }

    // ---- fused finalize: last block of node n applies mean+root+bias+relu ----
    __threadfence();                              // release this block's adds
    if (tid == 0) lastf = (atomicAdd(&done[n], 1) == G - 1) ? 1 : 0;
    __syncthreads();
    if (lastf) {
        __threadfence();                          // acquire all blocks' adds
        if (tid < COUT) {
            float inv = 1.f / fmaxf((float)len, 1.f);
            float v = agg[n * COUT + tid] * inv;
#pragma unroll
            for (int ii = 0; ii < CIN; ii++)
                v = fmaf(hprev[n * CIN + ii], root[ii * COUT + tid], v);
            v += bias[tid];
            hout[n * COUT + tid] = fmaxf(v, 0.f);
        }
    }
}

// ---------------------------------------------------------------------------
// CBT: out[i,j] = sum_k |h3[i,k] - h3[j,k]|, h3 is [512,5]
// ---------------------------------------------------------------------------
__global__ __launch_bounds__(256) void cbt_kernel(const float* __restrict__ h3,
                                                  float* __restrict__ out) {
    __shared__ float lh[N_NODES * 5];
    int tid = threadIdx.x;
    for (int idx = tid; idx < N_NODES * 5; idx += 256) lh[idx] = h3[idx];
    __syncthreads();
    int i = blockIdx.x;
    float hi[5];
#pragma unroll
    for (int k = 0; k < 5; k++) hi[k] = lh[i * 5 + k];
    for (int j = tid; j < N_NODES; j += 256) {
        float sacc = 0.f;
#pragma unroll
        for (int k = 0; k < 5; k++) sacc += fabsf(hi[k] - lh[j * 5 + k]);
        out[i * N_NODES + j] = sacc;
    }
}

// ---------------------------------------------------------------------------
extern "C" void kernel_launch(void* const* d_in, const int* in_sizes, int n_in,
                              void* d_out, int out_size, void* d_ws, size_t ws_size,
                              hipStream_t stream) {
    const float* x = (const float*)d_in[0];
    const float* edge_attr = (const float*)d_in[1];
    const int* edge_index = (const int*)d_in[2];
    const float* We1 = (const float*)d_in[3];
    const float* be1 = (const float*)d_in[4];
    const float* root1 = (const float*)d_in[5];
    const float* b1 = (const float*)d_in[6];
    const float* We2 = (const float*)d_in[7];
    const float* be2 = (const float*)d_in[8];
    const float* root2 = (const float*)d_in[9];
    const float* b2 = (const float*)d_in[10];
    const float* We3 = (const float*)d_in[11];
    const float* be3 = (const float*)d_in[12];
    const float* root3 = (const float*)d_in[13];
    const float* b3 = (const float*)d_in[14];

    const int E = N_EDGES;
    const int* src = edge_index;
    const int* dst = edge_index + E;

    char* ws = (char*)d_ws;
    int* offs = (int*)(ws + 0);               // 513 ints
    int* tot = (int*)(ws + 2048);             // 512 ints (fits in offs pad)
    int* bcnt_t = (int*)(ws + 4096);          // 512*256 ints (transposed) -> ends 528384
    int* pre = (int*)(ws + 528384);           // 256*512 ints -> ends 1052672
    int4* ed4 = (int4*)(ws + 1052672);        // E*16B -> ends 5246976
    float* agg1 = (float*)(ws + 5246976);     // 512*36 -> 5320704
    float* agg2 = (float*)(ws + 5320704);     // 512*24 -> 5369856
    float* agg3 = (float*)(ws + 5369856);     // 512*5  -> 5380096
    float* h1 = (float*)(ws + 5380096);       // 512*36 -> 5453824
    float* h2 = (float*)(ws + 5453824);       // 512*24 -> 5502976
    float* h3 = (float*)(ws + 5502976);       // 512*5  -> 5513216

    // done counters alias the LAST 6 rows of bcnt_t (rows 506..511): consumed
    // as histogram by colscan (read-before-zero), then re-zeroed by colscan
    // before any edges kernel runs. No workspace growth.
    int* done1 = bcnt_t + 506 * NBLK;         // 512 ints
    int* done2 = bcnt_t + 508 * NBLK;         // 512 ints
    int* done3 = bcnt_t + 510 * NBLK;         // 512 ints

    count_kernel<<<NBLK, 256, 0, stream>>>(dst, bcnt_t, agg1 /*contig agg region*/);
    colscan_kernel<<<N_NODES, NBLK, 0, stream>>>(bcnt_t, pre, tot, bcnt_t);
    offs_kernel<<<1, 512, 0, stream>>>(tot, offs);
    scatter_kernel<<<NBLK, 256, 0, stream>>>(src, dst, edge_attr, pre, offs, ed4);

    // L1: CIN=1, COUT=36, OG=1 -> A=36, BLK=64, G=16
    nnconv_edges<1, 36, 1, 64, 16><<<N_NODES * 16, 64, 0, stream>>>(
        x, ed4, offs, We1, be1, root1, b1, agg1, done1, h1);

    // L2: CIN=36, COUT=24, OG=8 -> OPL=3, A=108, BLK=128, G=8
    //     2 waves per edge (was 4) -> per-edge issue count cut ~15%,
    //     per-wave memory ops per edge halved.
    nnconv_edges<36, 24, 8, 128, 8><<<N_NODES * 8, 128, 0, stream>>>(
        h1, ed4, offs, We2, be2, root2, b2, agg2, done2, h2);

    // L3: CIN=24, COUT=5, OG=1 -> A=120, BLK=128, G=8
    nnconv_edges<24, 5, 1, 128, 8><<<N_NODES * 8, 128, 0, stream>>>(
        h2, ed4, offs, We3, be3, root3, b3, agg3, done3, h3);

    cbt_kernel<<<N_NODES, 256, 0, stream>>>(h3, (float*)d_out);
}

// Round 5
// 284.902 us; speedup vs baseline: 2.4002x; 2.4002x over previous
//
#include <hip/hip_runtime.h>
#include <hip/hip_bf16.h>

#define N_NODES 512
#define N_EDGES (512 * 512)
#define NBLK 256                 // sort blocks
#define EPB (N_EDGES / NBLK)     // 1024 edges per sort block

typedef __attribute__((ext_vector_type(2))) _Float16 half2v;

#if defined(__has_builtin)
#if __has_builtin(__builtin_amdgcn_fdot2)
#define FDOT2(a, b, c) __builtin_amdgcn_fdot2((a), (b), (c), false)
#endif
#endif
#ifndef FDOT2
static __device__ inline float fdot2_asm(half2v a, half2v b, float c) {
    float d;
    asm("v_dot2_f32_f16 %0, %1, %2, %3" : "=v"(d) : "v"(a), "v"(b), "v"(c));
    return d;
}
#define FDOT2(a, b, c) fdot2_asm((a), (b), (c))
#endif

static __device__ inline unsigned pack_h2(float x, float y) {
    union { _Float16 h[2]; unsigned u; } c;
    c.h[0] = (_Float16)x;
    c.h[1] = (_Float16)y;
    return c.u;
}
static __device__ inline half2v bits_h2(int b) {
    union { int i; half2v h; } c;
    c.i = b;
    return c.h;
}

// ---------------------------------------------------------------------------
// count: per-block LDS histogram -> TRANSPOSED bcnt_t[bucket][block] (coalesced
// colscan reads). Also zeros the agg1/agg2/agg3 region (replaces memsetAsync).
// ---------------------------------------------------------------------------
__global__ __launch_bounds__(256) void count_kernel(const int* __restrict__ dst,
                                                    int* __restrict__ bcnt_t,
                                                    float* __restrict__ aggz) {
    __shared__ int h[N_NODES];
    int tid = threadIdx.x;
    int b = blockIdx.x;
    h[tid] = 0;
    h[tid + 256] = 0;
    int gt = b * 256 + tid;
    if (gt < 512 * (36 + 24 + 5)) aggz[gt] = 0.f;   // zero aggs (contiguous)
    __syncthreads();
#pragma unroll
    for (int k = 0; k < EPB / 256; k++)
        atomicAdd(&h[dst[b * EPB + k * 256 + tid]], 1);
    __syncthreads();
    bcnt_t[tid * NBLK + b] = h[tid];
    bcnt_t[(tid + 256) * NBLK + b] = h[tid + 256];
}

// colscan: one block per bucket t. Coalesced read; exclusive prefix over sort
// blocks -> pre[b][t]; bucket total -> tot[t].
__global__ __launch_bounds__(NBLK) void colscan_kernel(const int* __restrict__ bcnt_t,
                                                       int* __restrict__ pre,
                                                       int* __restrict__ tot) {
    __shared__ int buf[NBLK];
    int t = blockIdx.x;
    int b = threadIdx.x;
    int v = bcnt_t[t * NBLK + b];                   // coalesced
    buf[b] = v;
    __syncthreads();
    for (int d = 1; d < NBLK; d <<= 1) {
        int add = (b >= d) ? buf[b - d] : 0;
        __syncthreads();
        buf[b] += add;
        __syncthreads();
    }
    pre[b * N_NODES + t] = buf[b] - v;
    if (b == NBLK - 1) tot[t] = buf[b];
}

// offs: scan of 512 bucket totals -> offs[513].
__global__ __launch_bounds__(512) void offs_kernel(const int* __restrict__ tot,
                                                   int* __restrict__ offs) {
    __shared__ int buf[N_NODES];
    int t = threadIdx.x;
    int v = tot[t];
    buf[t] = v;
    __syncthreads();
    for (int d = 1; d < N_NODES; d <<= 1) {
        int add = (t >= d) ? buf[t - d] : 0;
        __syncthreads();
        buf[t] += add;
        __syncthreads();
    }
    offs[t + 1] = buf[t];
    if (t == 0) offs[0] = 0;
}

// scatter: LDS cursor seeded from offs[t] + pre[b][t]; LDS atomics only.
__global__ __launch_bounds__(256) void scatter_kernel(const int* __restrict__ src,
                                                      const int* __restrict__ dst,
                                                      const float* __restrict__ ea,
                                                      const int* __restrict__ pre,
                                                      const int* __restrict__ offs,
                                                      int4* __restrict__ ed4) {
    __shared__ int lcur[N_NODES];
    int tid = threadIdx.x;
    int b = blockIdx.x;
    lcur[tid] = offs[tid] + pre[b * N_NODES + tid];
    lcur[tid + 256] = offs[tid + 256] + pre[b * N_NODES + tid + 256];
    __syncthreads();
#pragma unroll
    for (int k = 0; k < EPB / 256; k++) {
        int e = b * EPB + k * 256 + tid;
        const float* a = ea + (size_t)e * 6;
        float a0 = a[0], a1 = a[1], a2 = a[2], a3 = a[3], a4 = a[4], a5 = a[5];
        int p = atomicAdd(&lcur[dst[e]], 1);
        int4 r;
        r.x = (int)pack_h2(a0, a1);
        r.y = (int)pack_h2(a2, a3);
        r.z = (int)pack_h2(a4, a5);
        r.w = src[e];
        ed4[p] = r;
    }
}

// ---------------------------------------------------------------------------
// NNConv edge pipeline, hprev staged in LDS (the gather — the only in-loop
// VMEM latency — becomes a conflict-free LDS broadcast of consecutive words).
// CIN_T = full input width (hprev row stride); CIN_L = this block's slice
// (NH = CIN_T/CIN_L block-halves; the i-sum is linear so halves combine via
// the existing global atomicAdd). Lane t (<A) owns local feature il = t/OPL
// and OG consecutive outputs. Records load uniform (scalarized to SMEM).
// No device fences anywhere (R4 lesson).
// ---------------------------------------------------------------------------
template <int CIN_T, int CIN_L, int COUT, int OG, int BLK, int G, int NH>
__global__ __launch_bounds__(BLK) void nnconv_edges(
    const float* __restrict__ hprev,  // [512, CIN_T]
    const int4* __restrict__ ed4,     // [E] sorted-by-dst edge records
    const int* __restrict__ offs,     // [513]
    const float* __restrict__ We,     // [6, CIN_T*COUT]
    const float* __restrict__ be,     // [CIN_T*COUT]
    float* __restrict__ agg)          // [512, COUT] pre-zeroed
{
    constexpr int J = CIN_T * COUT;   // full per-view weight block
    constexpr int JL = CIN_L * COUT;  // local reduce buffer
    constexpr int OPL = COUT / OG;    // o-groups per input feature
    constexpr int A = CIN_L * OPL;    // active lanes

    __shared__ float lh[N_NODES * CIN_L];
    __shared__ float lds_acc[JL];

    const int bid = blockIdx.x;
    const int n = bid / (G * NH);
    const int rem = bid % (G * NH);
    const int g = rem / NH;
    const int hf = rem % NH;
    const int tid = threadIdx.x;
    const bool act = (tid < A);
    const int il = act ? tid / OPL : 0;        // local input feature
    const int ig = hf * CIN_L + il;            // global input feature
    const int og = act ? (tid % OPL) * OG : 0;

    // ---- stage hprev slice into LDS ----
    if constexpr (CIN_T == CIN_L) {
        constexpr int NF4 = N_NODES * CIN_L / 4;   // contiguous: float4 copy
        const float4* s4 = (const float4*)hprev;
        float4* d4 = (float4*)lh;
        for (int idx = tid; idx < NF4; idx += BLK) d4[idx] = s4[idx];
    } else {
        constexpr int CL2 = CIN_L / 2;             // strided half: float2 copy
        constexpr int NF2 = N_NODES * CL2;
        for (int idx = tid; idx < NF2; idx += BLK) {
            int r = idx / CL2;
            int c = idx - r * CL2;
            *((float2*)lh + idx) =
                *(const float2*)(hprev + hf * CIN_L + r * CIN_T + 2 * c);
        }
    }

    half2v wrp[OG][3];
    float ber[OG], acc[OG];
#pragma unroll
    for (int k = 0; k < OG; k++) {
        acc[k] = 0.f;
        int j = ig * COUT + og + k;
        if (act) {
            ber[k] = be[j];
#pragma unroll
            for (int t = 0; t < 3; t++)
                wrp[k][t] = bits_h2((int)pack_h2(We[(2 * t) * J + j], We[(2 * t + 1) * J + j]));
        } else {
            ber[k] = 0.f;
#pragma unroll
            for (int t = 0; t < 3; t++) wrp[k][t] = bits_h2(0);
        }
    }
    __syncthreads();                       // lh ready

    const int start = offs[n];
    const int end = offs[n + 1];
    const int len = end - start;
    const int per = (len + G - 1) / G;
    int p = start + g * per;
    int p1 = p + per;
    if (p > end) p = end;
    if (p1 > end) p1 = end;

    // full 8-edge groups: uniform record loads (SMEM), 8 independent LDS
    // broadcast gathers, then 8x compute — ILP 8 covers LDS/SMEM latency.
    for (; p + 8 <= p1; p += 8) {
        int4 e[8];
#pragma unroll
        for (int u = 0; u < 8; u++) e[u] = ed4[p + u];
        float xg[8];
#pragma unroll
        for (int u = 0; u < 8; u++) xg[u] = lh[(e[u].w & (N_NODES - 1)) * CIN_L + il];
#pragma unroll
        for (int u = 0; u < 8; u++) {
            half2v e01 = bits_h2(e[u].x), e23 = bits_h2(e[u].y), e45 = bits_h2(e[u].z);
#pragma unroll
            for (int k = 0; k < OG; k++) {
                float z = FDOT2(e45, wrp[k][2],
                        FDOT2(e23, wrp[k][1],
                        FDOT2(e01, wrp[k][0], ber[k])));
                acc[k] = fmaf(xg[u], fmaxf(z, 0.f), acc[k]);
            }
        }
    }
    // masked final group (uniform mask): zero record -> z=be finite, x=0 ->
    // contribution exactly 0.
    if (p < p1) {
        int4 e[8];
        float xg[8];
#pragma unroll
        for (int u = 0; u < 8; u++)
            e[u] = (p + u < p1) ? ed4[p + u] : make_int4(0, 0, 0, 0);
#pragma unroll
        for (int u = 0; u < 8; u++)
            xg[u] = (p + u < p1) ? lh[(e[u].w & (N_NODES - 1)) * CIN_L + il] : 0.f;
#pragma unroll
        for (int u = 0; u < 8; u++) {
            half2v e01 = bits_h2(e[u].x), e23 = bits_h2(e[u].y), e45 = bits_h2(e[u].z);
#pragma unroll
            for (int k = 0; k < OG; k++) {
                float z = FDOT2(e45, wrp[k][2],
                        FDOT2(e23, wrp[k][1],
                        FDOT2(e01, wrp[k][0], ber[k])));
                acc[k] = fmaf(xg[u], fmaxf(z, 0.f), acc[k]);
            }
        }
    }

    // ---- combine partials into agg[n] ----
    if constexpr (CIN_T == 1) {
        if (act) atomicAdd(&agg[n * COUT + og], acc[0]);
    } else {
        if (act) {
#pragma unroll
            for (int k = 0; k < OG; k++) lds_acc[il * COUT + og + k] = acc[k];
        }
        __syncthreads();
        if (tid < COUT) {
            float sum = 0.f;
#pragma unroll
            for (int ii = 0; ii < CIN_L; ii++) sum += lds_acc[ii * COUT + tid];
            atomicAdd(&agg[n * COUT + tid], sum);
        }
    }
}

// ---------------------------------------------------------------------------
// Finalize: mean + root-weight + bias + relu (separate tiny launch — R4's
// fence-fused variant serialized the memory system; never again)
// ---------------------------------------------------------------------------
template <int CIN, int COUT>
__global__ __launch_bounds__(64) void nnconv_fin(const float* __restrict__ agg,
                                                 const int* __restrict__ offs,
                                                 const float* __restrict__ hprev,
                                                 const float* __restrict__ root,
                                                 const float* __restrict__ bias,
                                                 float* __restrict__ hout) {
    int n = blockIdx.x;
    int t = threadIdx.x;
    if (t >= COUT) return;
    int cnt = offs[n + 1] - offs[n];
    float inv = 1.f / fmaxf((float)cnt, 1.f);
    float v = agg[n * COUT + t] * inv;
#pragma unroll
    for (int i = 0; i < CIN; i++) v = fmaf(hprev[n * CIN + i], root[i * COUT + t], v);
    v += bias[t];
    hout[n * COUT + t] = fmaxf(v, 0.f);
}

// ---------------------------------------------------------------------------
// CBT: out[i,j] = sum_k |h3[i,k] - h3[j,k]|, h3 is [512,5]
// ---------------------------------------------------------------------------
__global__ __launch_bounds__(256) void cbt_kernel(const float* __restrict__ h3,
                                                  float* __restrict__ out) {
    __shared__ float lh[N_NODES * 5];
    int tid = threadIdx.x;
    for (int idx = tid; idx < N_NODES * 5; idx += 256) lh[idx] = h3[idx];
    __syncthreads();
    int i = blockIdx.x;
    float hi[5];
#pragma unroll
    for (int k = 0; k < 5; k++) hi[k] = lh[i * 5 + k];
    for (int j = tid; j < N_NODES; j += 256) {
        float sacc = 0.f;
#pragma unroll
        for (int k = 0; k < 5; k++) sacc += fabsf(hi[k] - lh[j * 5 + k]);
        out[i * N_NODES + j] = sacc;
    }
}

// ---------------------------------------------------------------------------
extern "C" void kernel_launch(void* const* d_in, const int* in_sizes, int n_in,
                              void* d_out, int out_size, void* d_ws, size_t ws_size,
                              hipStream_t stream) {
    const float* x = (const float*)d_in[0];
    const float* edge_attr = (const float*)d_in[1];
    const int* edge_index = (const int*)d_in[2];
    const float* We1 = (const float*)d_in[3];
    const float* be1 = (const float*)d_in[4];
    const float* root1 = (const float*)d_in[5];
    const float* b1 = (const float*)d_in[6];
    const float* We2 = (const float*)d_in[7];
    const float* be2 = (const float*)d_in[8];
    const float* root2 = (const float*)d_in[9];
    const float* b2 = (const float*)d_in[10];
    const float* We3 = (const float*)d_in[11];
    const float* be3 = (const float*)d_in[12];
    const float* root3 = (const float*)d_in[13];
    const float* b3 = (const float*)d_in[14];

    const int E = N_EDGES;
    const int* src = edge_index;
    const int* dst = edge_index + E;

    char* ws = (char*)d_ws;
    int* offs = (int*)(ws + 0);               // 513 ints
    int* tot = (int*)(ws + 2048);             // 512 ints (fits in offs pad)
    int* bcnt_t = (int*)(ws + 4096);          // 512*256 ints (transposed) -> ends 528384
    int* pre = (int*)(ws + 528384);           // 256*512 ints -> ends 1052672
    int4* ed4 = (int4*)(ws + 1052672);        // E*16B -> ends 5246976
    float* agg1 = (float*)(ws + 5246976);     // 512*36 -> 5320704
    float* agg2 = (float*)(ws + 5320704);     // 512*24 -> 5369856
    float* agg3 = (float*)(ws + 5369856);     // 512*5  -> 5380096
    float* h1 = (float*)(ws + 5380096);       // 512*36 -> 5453824
    float* h2 = (float*)(ws + 5453824);       // 512*24 -> 5502976
    float* h3 = (float*)(ws + 5502976);       // 512*5  -> 5513216

    count_kernel<<<NBLK, 256, 0, stream>>>(dst, bcnt_t, agg1 /*contig agg region*/);
    colscan_kernel<<<N_NODES, NBLK, 0, stream>>>(bcnt_t, pre, tot);
    offs_kernel<<<1, 512, 0, stream>>>(tot, offs);
    scatter_kernel<<<NBLK, 256, 0, stream>>>(src, dst, edge_attr, pre, offs, ed4);

    // L1: CIN 1, COUT=36, OG=1 -> A=36, BLK=64, G=16, no split. lh = 2KB.
    nnconv_edges<1, 1, 36, 1, 64, 16, 1><<<N_NODES * 16, 64, 0, stream>>>(
        x, ed4, offs, We1, be1, agg1);
    nnconv_fin<1, 36><<<N_NODES, 64, 0, stream>>>(agg1, offs, x, root1, b1, h1);

    // L2: CIN 36 split in 2 halves of 18 (h1 = 73KB > 64KB static-LDS cap;
    // half = 36KB). OG=4 -> OPL=6, A=108, BLK=128, G=4 -> grid 4096.
    nnconv_edges<36, 18, 24, 4, 128, 4, 2><<<N_NODES * 8, 128, 0, stream>>>(
        h1, ed4, offs, We2, be2, agg2);
    nnconv_fin<36, 24><<<N_NODES, 64, 0, stream>>>(agg2, offs, h1, root2, b2, h2);

    // L3: CIN 24, COUT=5, OG=1 -> A=120, BLK=128, G=4, no split. lh = 49KB.
    nnconv_edges<24, 24, 5, 1, 128, 4, 1><<<N_NODES * 4, 128, 0, stream>>>(
        h2, ed4, offs, We3, be3, agg3);
    nnconv_fin<24, 5><<<N_NODES, 64, 0, stream>>>(agg3, offs, h2, root3, b3, h3);

    cbt_kernel<<<N_NODES, 256, 0, stream>>>(h3, (float*)d_out);
}

// Round 7
// 193.313 us; speedup vs baseline: 3.5374x; 1.4738x over previous
//
#include <hip/hip_runtime.h>
#include <hip/hip_bf16.h>

#define N_NODES 512
#define N_EDGES (512 * 512)
#define NBLK 256                 // sort blocks
#define EPB (N_EDGES / NBLK)     // 1024 edges per sort block

typedef __attribute__((ext_vector_type(2))) _Float16 half2v;

#if defined(__has_builtin)
#if __has_builtin(__builtin_amdgcn_fdot2)
#define FDOT2(a, b, c) __builtin_amdgcn_fdot2((a), (b), (c), false)
#endif
#endif
#ifndef FDOT2
static __device__ inline float fdot2_asm(half2v a, half2v b, float c) {
    float d;
    asm("v_dot2_f32_f16 %0, %1, %2, %3" : "=v"(d) : "v"(a), "v"(b), "v"(c));
    return d;
}
#define FDOT2(a, b, c) fdot2_asm((a), (b), (c))
#endif

static __device__ inline unsigned pack_h2(float x, float y) {
    union { _Float16 h[2]; unsigned u; } c;
    c.h[0] = (_Float16)x;
    c.h[1] = (_Float16)y;
    return c.u;
}
static __device__ inline half2v bits_h2(int b) {
    union { int i; half2v h; } c;
    c.i = b;
    return c.h;
}

// ---------------------------------------------------------------------------
// count: per-block LDS histogram -> TRANSPOSED bcnt_t[bucket][block] (coalesced
// colscan reads). Also zeros the agg1/agg2/agg3 region (replaces memsetAsync).
// ---------------------------------------------------------------------------
__global__ __launch_bounds__(256) void count_kernel(const int* __restrict__ dst,
                                                    int* __restrict__ bcnt_t,
                                                    float* __restrict__ aggz) {
    __shared__ int h[N_NODES];
    int tid = threadIdx.x;
    int b = blockIdx.x;
    h[tid] = 0;
    h[tid + 256] = 0;
    int gt = b * 256 + tid;
    if (gt < 512 * (36 + 24 + 5)) aggz[gt] = 0.f;   // zero aggs (contiguous)
    __syncthreads();
#pragma unroll
    for (int k = 0; k < EPB / 256; k++)
        atomicAdd(&h[dst[b * EPB + k * 256 + tid]], 1);
    __syncthreads();
    bcnt_t[tid * NBLK + b] = h[tid];
    bcnt_t[(tid + 256) * NBLK + b] = h[tid + 256];
}

// colscan: one block per bucket t. Coalesced read; exclusive prefix over sort
// blocks -> pre[b][t]; bucket total -> tot[t].
__global__ __launch_bounds__(NBLK) void colscan_kernel(const int* __restrict__ bcnt_t,
                                                       int* __restrict__ pre,
                                                       int* __restrict__ tot) {
    __shared__ int buf[NBLK];
    int t = blockIdx.x;
    int b = threadIdx.x;
    int v = bcnt_t[t * NBLK + b];                   // coalesced
    buf[b] = v;
    __syncthreads();
    for (int d = 1; d < NBLK; d <<= 1) {
        int add = (b >= d) ? buf[b - d] : 0;
        __syncthreads();
        buf[b] += add;
        __syncthreads();
    }
    pre[b * N_NODES + t] = buf[b] - v;
    if (b == NBLK - 1) tot[t] = buf[b];
}

// offs: scan of 512 bucket totals -> offs[513].
__global__ __launch_bounds__(512) void offs_kernel(const int* __restrict__ tot,
                                                   int* __restrict__ offs) {
    __shared__ int buf[N_NODES];
    int t = threadIdx.x;
    int v = tot[t];
    buf[t] = v;
    __syncthreads();
    for (int d = 1; d < N_NODES; d <<= 1) {
        int add = (t >= d) ? buf[t - d] : 0;
        __syncthreads();
        buf[t] += add;
        __syncthreads();
    }
    offs[t + 1] = buf[t];
    if (t == 0) offs[0] = 0;
}

// scatter: LDS cursor seeded from offs[t] + pre[b][t]; LDS atomics only.
__global__ __launch_bounds__(256) void scatter_kernel(const int* __restrict__ src,
                                                      const int* __restrict__ dst,
                                                      const float* __restrict__ ea,
                                                      const int* __restrict__ pre,
                                                      const int* __restrict__ offs,
                                                      int4* __restrict__ ed4) {
    __shared__ int lcur[N_NODES];
    int tid = threadIdx.x;
    int b = blockIdx.x;
    lcur[tid] = offs[tid] + pre[b * N_NODES + tid];
    lcur[tid + 256] = offs[tid + 256] + pre[b * N_NODES + tid + 256];
    __syncthreads();
#pragma unroll
    for (int k = 0; k < EPB / 256; k++) {
        int e = b * EPB + k * 256 + tid;
        const float* a = ea + (size_t)e * 6;
        float a0 = a[0], a1 = a[1], a2 = a[2], a3 = a[3], a4 = a[4], a5 = a[5];
        int p = atomicAdd(&lcur[dst[e]], 1);
        int4 r;
        r.x = (int)pack_h2(a0, a1);
        r.y = (int)pack_h2(a2, a3);
        r.z = (int)pack_h2(a4, a5);
        r.w = src[e];
        ed4[p] = r;
    }
}

// ---------------------------------------------------------------------------
// L1 special (CIN=1): lane-parallel over EDGES. Lane l = (e_sub = l>>2,
// oq = l&3); each lane computes 9 outputs (o = oq*9+q) for ITS OWN edge.
// Per wave pass: 16 edges, ONE coalesced record load (4 lanes share a 16B
// record -> broadcast), one gather/lane, 45 core inst. 100% lane util
// (old layout: A=36/64, 5 wave-inst/edge, 16 chained scalar loads/group).
// Epilogue: butterfly shfl reduce over e_sub, LDS atomic, global atomic.
// ---------------------------------------------------------------------------
__global__ __launch_bounds__(256) void nnconv_l1(const float* __restrict__ x,
                                                 const int4* __restrict__ ed4,
                                                 const int* __restrict__ offs,
                                                 const float* __restrict__ We,  // [6,36]
                                                 const float* __restrict__ be,  // [36]
                                                 float* __restrict__ agg) {     // [512,36]
    constexpr int G = 2;
    __shared__ float lacc[36];
    const int n = blockIdx.x / G;
    const int g = blockIdx.x % G;
    const int tid = threadIdx.x;
    const int w = tid >> 6;          // wave 0..3
    const int lane = tid & 63;
    const int es = lane >> 2;        // edge sub-slot 0..15
    const int oq = lane & 3;         // output quarter 0..3

    half2v wrp[9][3];
    float ber[9], acc[9];
#pragma unroll
    for (int q = 0; q < 9; q++) {
        int o = oq * 9 + q;
        ber[q] = be[o];
        acc[q] = 0.f;
#pragma unroll
        for (int t = 0; t < 3; t++)
            wrp[q][t] = bits_h2((int)pack_h2(We[(2 * t) * 36 + o], We[(2 * t + 1) * 36 + o]));
    }

    const int start = offs[n];
    const int end = offs[n + 1];
    const int len = end - start;
    const int per = (len + G - 1) / G;
    int p0 = start + g * per;
    int p1 = p0 + per;
    if (p0 > end) p0 = end;
    if (p1 > end) p1 = end;

    // wave w handles 16-edge groups w, w+4, w+8, ... of this slice
    for (int p = p0 + w * 16; p < p1; p += 64) {
        bool v = (p + es) < p1;
        int4 e = v ? ed4[p + es] : make_int4(0, 0, 0, 0);
        float xv = v ? x[e.w & (N_NODES - 1)] : 0.f;
        half2v e01 = bits_h2(e.x), e23 = bits_h2(e.y), e45 = bits_h2(e.z);
#pragma unroll
        for (int q = 0; q < 9; q++) {
            float z = FDOT2(e45, wrp[q][2],
                    FDOT2(e23, wrp[q][1],
                    FDOT2(e01, wrp[q][0], ber[q])));
            acc[q] = fmaf(xv, fmaxf(z, 0.f), acc[q]);
        }
    }

    // butterfly reduce across e_sub (stride-4 lane classes; oq bits preserved)
#pragma unroll
    for (int m = 4; m <= 32; m <<= 1) {
#pragma unroll
        for (int q = 0; q < 9; q++) acc[q] += __shfl_xor(acc[q], m, 64);
    }

    if (tid < 36) lacc[tid] = 0.f;
    __syncthreads();
    if (lane < 4) {  // es == 0 holds the per-wave sums
#pragma unroll
        for (int q = 0; q < 9; q++) atomicAdd(&lacc[oq * 9 + q], acc[q]);
    }
    __syncthreads();
    if (tid < 36) atomicAdd(&agg[n * 36 + tid], lacc[tid]);
}

// ---------------------------------------------------------------------------
// Generic NNConv edge pipeline (L2/L3): R2-proven direct-load form. Lane t
// (<A) owns input-feature i = t/OPL and OG consecutive outputs. Uniform
// record loads (scalarized to SMEM), 8-edge groups, masked final group.
// ---------------------------------------------------------------------------
template <int CIN, int COUT, int OG, int BLK, int G>
__global__ __launch_bounds__(BLK) void nnconv_edges(
    const float* __restrict__ hprev,  // [512, CIN]
    const int4* __restrict__ ed4,     // [E] sorted-by-dst edge records
    const int* __restrict__ offs,     // [513]
    const float* __restrict__ We,     // [6, CIN*COUT]
    const float* __restrict__ be,     // [CIN*COUT]
    float* __restrict__ agg)          // [512, COUT] pre-zeroed
{
    constexpr int J = CIN * COUT;
    constexpr int OPL = COUT / OG;   // o-groups per input feature
    constexpr int A = CIN * OPL;     // active lanes

    const int n = blockIdx.x / G;
    const int g = blockIdx.x % G;
    const int tid = threadIdx.x;
    const bool act = (tid < A);
    const int i = act ? tid / OPL : 0;
    const int og = act ? (tid % OPL) * OG : 0;

    half2v wrp[OG][3];
    float ber[OG], acc[OG];
#pragma unroll
    for (int k = 0; k < OG; k++) {
        acc[k] = 0.f;
        int j = i * COUT + og + k;
        if (act) {
            ber[k] = be[j];
#pragma unroll
            for (int t = 0; t < 3; t++)
                wrp[k][t] = bits_h2((int)pack_h2(We[(2 * t) * J + j], We[(2 * t + 1) * J + j]));
        } else {
            ber[k] = 0.f;
#pragma unroll
            for (int t = 0; t < 3; t++) wrp[k][t] = bits_h2(0);
        }
    }

    const int start = offs[n];
    const int end = offs[n + 1];
    const int len = end - start;
    const int per = (len + G - 1) / G;
    int p = start + g * per;
    int p1 = p + per;
    if (p > end) p = end;
    if (p1 > end) p1 = end;

    const float* hp_i = hprev + i;   // per-lane feature-column base

    for (; p + 8 <= p1; p += 8) {
        int4 e[8];
#pragma unroll
        for (int u = 0; u < 8; u++) e[u] = ed4[p + u];
        float xg[8];
#pragma unroll
        for (int u = 0; u < 8; u++) xg[u] = hp_i[(e[u].w & (N_NODES - 1)) * CIN];
#pragma unroll
        for (int u = 0; u < 8; u++) {
            half2v e01 = bits_h2(e[u].x), e23 = bits_h2(e[u].y), e45 = bits_h2(e[u].z);
#pragma unroll
            for (int k = 0; k < OG; k++) {
                float z = FDOT2(e45, wrp[k][2],
                        FDOT2(e23, wrp[k][1],
                        FDOT2(e01, wrp[k][0], ber[k])));
                acc[k] = fmaf(xg[u], fmaxf(z, 0.f), acc[k]);
            }
        }
    }
    // masked final group (uniform mask): zero record -> z=be finite, x=0 ->
    // contribution exactly 0.
    if (p < p1) {
        int4 e[8];
        float xg[8];
#pragma unroll
        for (int u = 0; u < 8; u++)
            e[u] = (p + u < p1) ? ed4[p + u] : make_int4(0, 0, 0, 0);
#pragma unroll
        for (int u = 0; u < 8; u++)
            xg[u] = (p + u < p1) ? hp_i[(e[u].w & (N_NODES - 1)) * CIN] : 0.f;
#pragma unroll
        for (int u = 0; u < 8; u++) {
            half2v e01 = bits_h2(e[u].x), e23 = bits_h2(e[u].y), e45 = bits_h2(e[u].z);
#pragma unroll
            for (int k = 0; k < OG; k++) {
                float z = FDOT2(e45, wrp[k][2],
                        FDOT2(e23, wrp[k][1],
                        FDOT2(e01, wrp[k][0], ber[k])));
                acc[k] = fmaf(xg[u], fmaxf(z, 0.f), acc[k]);
            }
        }
    }

    // ---- combine partials into agg[n] ----
    __shared__ float lds_acc[J];
    if (act) {
#pragma unroll
        for (int k = 0; k < OG; k++) lds_acc[i * COUT + og + k] = acc[k];
    }
    __syncthreads();
    if (tid < COUT) {
        float sum = 0.f;
#pragma unroll
        for (int ii = 0; ii < CIN; ii++) sum += lds_acc[ii * COUT + tid];
        atomicAdd(&agg[n * COUT + tid], sum);
    }
}

// ---------------------------------------------------------------------------
// Finalize: mean + root-weight + bias + relu (separate tiny launch — R4's
// fence-fused variant serialized the memory system; never again)
// ---------------------------------------------------------------------------
template <int CIN, int COUT>
__global__ __launch_bounds__(64) void nnconv_fin(const float* __restrict__ agg,
                                                 const int* __restrict__ offs,
                                                 const float* __restrict__ hprev,
                                                 const float* __restrict__ root,
                                                 const float* __restrict__ bias,
                                                 float* __restrict__ hout) {
    int n = blockIdx.x;
    int t = threadIdx.x;
    if (t >= COUT) return;
    int cnt = offs[n + 1] - offs[n];
    float inv = 1.f / fmaxf((float)cnt, 1.f);
    float v = agg[n * COUT + t] * inv;
#pragma unroll
    for (int i = 0; i < CIN; i++) v = fmaf(hprev[n * CIN + i], root[i * COUT + t], v);
    v += bias[t];
    hout[n * COUT + t] = fmaxf(v, 0.f);
}

// ---------------------------------------------------------------------------
// CBT: out[i,j] = sum_k |h3[i,k] - h3[j,k]|, h3 is [512,5]
// ---------------------------------------------------------------------------
__global__ __launch_bounds__(256) void cbt_kernel(const float* __restrict__ h3,
                                                  float* __restrict__ out) {
    __shared__ float lh[N_NODES * 5];
    int tid = threadIdx.x;
    for (int idx = tid; idx < N_NODES * 5; idx += 256) lh[idx] = h3[idx];
    __syncthreads();
    int i = blockIdx.x;
    float hi[5];
#pragma unroll
    for (int k = 0; k < 5; k++) hi[k] = lh[i * 5 + k];
    for (int j = tid; j < N_NODES; j += 256) {
        float sacc = 0.f;
#pragma unroll
        for (int k = 0; k < 5; k++) sacc += fabsf(hi[k] - lh[j * 5 + k]);
        out[i * N_NODES + j] = sacc;
    }
}

// ---------------------------------------------------------------------------
extern "C" void kernel_launch(void* const* d_in, const int* in_sizes, int n_in,
                              void* d_out, int out_size, void* d_ws, size_t ws_size,
                              hipStream_t stream) {
    const float* x = (const float*)d_in[0];
    const float* edge_attr = (const float*)d_in[1];
    const int* edge_index = (const int*)d_in[2];
    const float* We1 = (const float*)d_in[3];
    const float* be1 = (const float*)d_in[4];
    const float* root1 = (const float*)d_in[5];
    const float* b1 = (const float*)d_in[6];
    const float* We2 = (const float*)d_in[7];
    const float* be2 = (const float*)d_in[8];
    const float* root2 = (const float*)d_in[9];
    const float* b2 = (const float*)d_in[10];
    const float* We3 = (const float*)d_in[11];
    const float* be3 = (const float*)d_in[12];
    const float* root3 = (const float*)d_in[13];
    const float* b3 = (const float*)d_in[14];

    const int E = N_EDGES;
    const int* src = edge_index;
    const int* dst = edge_index + E;

    char* ws = (char*)d_ws;
    int* offs = (int*)(ws + 0);               // 513 ints
    int* tot = (int*)(ws + 2048);             // 512 ints (fits in offs pad)
    int* bcnt_t = (int*)(ws + 4096);          // 512*256 ints (transposed) -> ends 528384
    int* pre = (int*)(ws + 528384);           // 256*512 ints -> ends 1052672
    int4* ed4 = (int4*)(ws + 1052672);        // E*16B -> ends 5246976
    float* agg1 = (float*)(ws + 5246976);     // 512*36 -> 5320704
    float* agg2 = (float*)(ws + 5320704);     // 512*24 -> 5369856
    float* agg3 = (float*)(ws + 5369856);     // 512*5  -> 5380096
    float* h1 = (float*)(ws + 5380096);       // 512*36 -> 5453824
    float* h2 = (float*)(ws + 5453824);       // 512*24 -> 5502976
    float* h3 = (float*)(ws + 5502976);       // 512*5  -> 5513216

    count_kernel<<<NBLK, 256, 0, stream>>>(dst, bcnt_t, agg1 /*contig agg region*/);
    colscan_kernel<<<N_NODES, NBLK, 0, stream>>>(bcnt_t, pre, tot);
    offs_kernel<<<1, 512, 0, stream>>>(tot, offs);
    scatter_kernel<<<NBLK, 256, 0, stream>>>(src, dst, edge_attr, pre, offs, ed4);

    // L1: edge-parallel special kernel. BLK=256 (4 waves x 16-edge groups), G=2.
    nnconv_l1<<<N_NODES * 2, 256, 0, stream>>>(x, ed4, offs, We1, be1, agg1);
    nnconv_fin<1, 36><<<N_NODES, 64, 0, stream>>>(agg1, offs, x, root1, b1, h1);

    // L2: R2-proven config: CIN=36, COUT=24, OG=4 -> A=216, BLK=256, G=8
    nnconv_edges<36, 24, 4, 256, 8><<<N_NODES * 8, 256, 0, stream>>>(h1, ed4, offs, We2, be2, agg2);
    nnconv_fin<36, 24><<<N_NODES, 64, 0, stream>>>(agg2, offs, h1, root2, b2, h2);

    // L3: R2-proven config: CIN=24, COUT=5, OG=1 -> A=120, BLK=128, G=8
    nnconv_edges<24, 5, 1, 128, 8><<<N_NODES * 8, 128, 0, stream>>>(h2, ed4, offs, We3, be3, agg3);
    nnconv_fin<24, 5><<<N_NODES, 64, 0, stream>>>(agg3, offs, h2, root3, b3, h3);

    cbt_kernel<<<N_NODES, 256, 0, stream>>>(h3, (float*)d_out);
}